// Round 1
// baseline (298.111 us; speedup 1.0000x reference)
//
#include <hip/hip_runtime.h>
#include <math.h>

#define BB  16
#define IDF 128
#define CDF 256
#define SL  48
#define QQ  16384   // 128*128

// ws layout (floats): srcT [B][IDF][SL] | sent [B][IDF] | wsvT [IDF][IDF] (i-major)
#define WS_SRCT 0
#define WS_SENT (BB*IDF*SL)
#define WS_WSVT (WS_SENT + BB*IDF)

__global__ __launch_bounds__(256) void prep_kernel(
    const float* __restrict__ context,   // [B][CDF][SL]
    const float* __restrict__ w_ctx,     // [IDF][CDF]
    const float* __restrict__ sentence,  // [B][100]
    const float* __restrict__ w_lin,     // [IDF][100]
    const float* __restrict__ b_lin,     // [IDF]
    const float* __restrict__ w_sv,      // [IDF][IDF] (o,i)
    float* __restrict__ srcT,            // [B][IDF][SL]
    float* __restrict__ sent,            // [B][IDF]
    float* __restrict__ wsvT)            // [IDF][IDF] (i,o)
{
    const int b    = blockIdx.x;
    const int iblk = blockIdx.y;       // 0..3, 32 output rows each
    const int t    = threadIdx.x;

    __shared__ float ctx_lds[CDF * SL];   // 48 KB
    __shared__ float w_lds[32 * CDF];     // 32 KB

    // stage context[b] (12288 floats)
    for (int r = 0; r < (CDF * SL) / 256; ++r) {
        int idx = r * 256 + t;
        ctx_lds[idx] = context[b * CDF * SL + idx];
    }
    // stage 32 rows of w_ctx
    const int i0 = iblk * 32;
    for (int r = 0; r < 32; ++r)
        w_lds[r * CDF + t] = w_ctx[(i0 + r) * CDF + t];
    __syncthreads();

    // srcT[b][i0+ii][s] = sum_c w_ctx[i0+ii][c] * context[b][c][s]
    for (int r = 0; r < 6; ++r) {
        int idx = r * 256 + t;          // 0..1535
        int ii = idx / SL, s = idx % SL;
        float a = 0.f;
        for (int c = 0; c < CDF; ++c)
            a += w_lds[ii * CDF + c] * ctx_lds[c * SL + s];
        srcT[(b * IDF + i0 + ii) * SL + s] = a;
    }

    // sent[b][o] = b_lin[o] + sentence[b]·w_lin[o]
    if (t < 32) {
        int o = iblk * 32 + t;
        float a = b_lin[o];
        for (int k = 0; k < 100; ++k)
            a += sentence[b * 100 + k] * w_lin[o * 100 + k];
        sent[b * IDF + o] = a;
    }

    // wsvT[i][o] = w_sv[o][i]  (only b==0 blocks)
    if (b == 0) {
        for (int r = 0; r < 16; ++r) {
            int idx = iblk * 4096 + r * 256 + t;
            int i = idx >> 7, o = idx & 127;
            wsvT[idx] = w_sv[o * IDF + i];
        }
    }
}

// Word-attention path: logits -> mask -> softmax -> word_attn + weightedContext
__global__ __launch_bounds__(256) void attn_kernel(
    const float* __restrict__ input,  // [B][IDF][Q]
    const float* __restrict__ srcT,   // [B][IDF][SL]
    const int*   __restrict__ mask,   // [B][SL]
    float* __restrict__ wctx,         // out0 [B][IDF][Q]
    float* __restrict__ wattn)        // out2 [B][SL][Q]
{
    const int bid = blockIdx.x;
    const int b   = bid >> 6;          // 64 q-tiles per batch
    const int qt  = bid & 63;
    const int q   = qt * 256 + threadIdx.x;

    const float* sT  = srcT + b * IDF * SL;   // block-uniform -> scalar loads
    const float* inp = input + (size_t)b * IDF * QQ + q;

    float acc[SL];
    #pragma unroll
    for (int s = 0; s < SL; ++s) acc[s] = 0.f;

    #pragma unroll 2
    for (int i = 0; i < IDF; ++i) {
        float v = inp[(size_t)i * QQ];
        const float* row = sT + i * SL;
        #pragma unroll
        for (int s = 0; s < SL; ++s) acc[s] += v * row[s];
    }

    // mask + softmax over s
    float m = -INFINITY;
    #pragma unroll
    for (int s = 0; s < SL; ++s) {
        if (mask[b * SL + s]) acc[s] = -INFINITY;
        m = fmaxf(m, acc[s]);
    }
    float sum = 0.f;
    #pragma unroll
    for (int s = 0; s < SL; ++s) { acc[s] = __expf(acc[s] - m); sum += acc[s]; }
    float inv = 1.f / sum;
    #pragma unroll
    for (int s = 0; s < SL; ++s) {
        acc[s] *= inv;
        wattn[((size_t)b * SL + s) * QQ + q] = acc[s];
    }

    // weightedContext[b][i][q] = sum_s srcT[b][i][s] * attn[s]
    for (int i = 0; i < IDF; ++i) {
        const float* row = sT + i * SL;
        float w = 0.f;
        #pragma unroll
        for (int s = 0; s < SL; ++s) w += row[s] * acc[s];
        wctx[((size_t)b * IDF + i) * QQ + q] = w;
    }
}

// Sentence path: sv = w_sv @ (input*sent), softmax over channels, outputs
__global__ __launch_bounds__(256) void sent_kernel(
    const float* __restrict__ input,  // [B][IDF][Q]
    const float* __restrict__ wsvT,   // [IDF(i)][IDF(o)]
    const float* __restrict__ sent,   // [B][IDF]
    float* __restrict__ wsent,        // out1 [B][IDF][Q]
    float* __restrict__ satt)         // out3 [B][IDF][Q]
{
    const int b  = blockIdx.x;
    const int q0 = blockIdx.y * 64;
    const int t  = threadIdx.x;

    __shared__ float xs[IDF * 64];     // 32 KB
    __shared__ float red[2][4][64];

    // stage x[i][q] = input[b,i,q0+q] * sent[b,i]
    for (int r = 0; r < 32; ++r) {
        int idx = r * 256 + t;
        int i = idx >> 6, qq = idx & 63;
        xs[idx] = input[((size_t)b * IDF + i) * QQ + q0 + qq] * sent[b * IDF + i];
    }
    __syncthreads();

    const int wave = __builtin_amdgcn_readfirstlane(t >> 6);  // 0..3
    const int lane = t & 63;

    float acc[32];
    #pragma unroll
    for (int oo = 0; oo < 32; ++oo) acc[oo] = 0.f;

    // acc[oo] = sum_i wsvT[i][wave*32+oo] * x[i][lane]
    const float* wT = wsvT + wave * 32;   // wave-uniform -> scalar loads
    for (int i = 0; i < IDF; ++i) {
        float v = xs[i * 64 + lane];
        #pragma unroll
        for (int oo = 0; oo < 32; ++oo)
            acc[oo] += wT[i * IDF + oo] * v;
    }

    // softmax over the 128 channels (32 per wave x 4 waves)
    float lmax = -INFINITY;
    #pragma unroll
    for (int oo = 0; oo < 32; ++oo) lmax = fmaxf(lmax, acc[oo]);
    red[0][wave][lane] = lmax;
    __syncthreads();
    float m = fmaxf(fmaxf(red[0][0][lane], red[0][1][lane]),
                    fmaxf(red[0][2][lane], red[0][3][lane]));
    float lsum = 0.f;
    #pragma unroll
    for (int oo = 0; oo < 32; ++oo) { acc[oo] = __expf(acc[oo] - m); lsum += acc[oo]; }
    red[1][wave][lane] = lsum;
    __syncthreads();
    float tot = red[1][0][lane] + red[1][1][lane] + red[1][2][lane] + red[1][3][lane];
    float inv = 1.f / tot;

    #pragma unroll
    for (int oo = 0; oo < 32; ++oo) {
        int o = wave * 32 + oo;
        float p = acc[oo] * inv;
        size_t off = ((size_t)b * IDF + o) * QQ + q0 + lane;
        satt[off]  = p;
        wsent[off] = sent[b * IDF + o] * p;
    }
}

extern "C" void kernel_launch(void* const* d_in, const int* in_sizes, int n_in,
                              void* d_out, int out_size, void* d_ws, size_t ws_size,
                              hipStream_t stream) {
    const float* input    = (const float*)d_in[0];
    const float* sentence = (const float*)d_in[1];
    const float* context  = (const float*)d_in[2];
    const int*   mask     = (const int*)d_in[3];
    const float* w_ctx    = (const float*)d_in[4];
    const float* w_sv     = (const float*)d_in[5];
    const float* w_lin    = (const float*)d_in[6];
    const float* b_lin    = (const float*)d_in[7];

    float* out = (float*)d_out;
    float* out_wctx  = out;                                   // [B][IDF][Q]
    float* out_wsent = out + (size_t)BB * IDF * QQ;           // [B][IDF][Q]
    float* out_wattn = out + 2 * (size_t)BB * IDF * QQ;       // [B][SL][Q]
    float* out_satt  = out_wattn + (size_t)BB * SL * QQ;      // [B][IDF][Q]

    float* ws   = (float*)d_ws;
    float* srcT = ws + WS_SRCT;
    float* sent = ws + WS_SENT;
    float* wsvT = ws + WS_WSVT;

    prep_kernel<<<dim3(16, 4), 256, 0, stream>>>(context, w_ctx, sentence,
                                                 w_lin, b_lin, w_sv,
                                                 srcT, sent, wsvT);
    attn_kernel<<<dim3(1024), 256, 0, stream>>>(input, srcT, mask,
                                                out_wctx, out_wattn);
    sent_kernel<<<dim3(16, 256), 256, 0, stream>>>(input, wsvT, sent,
                                                   out_wsent, out_satt);
}